// Round 1
// baseline (289.491 us; speedup 1.0000x reference)
//
#include <hip/hip_runtime.h>

// ---------- types ----------
typedef __bf16 bf16;
typedef __bf16 bf16x4 __attribute__((ext_vector_type(4)));
typedef __bf16 bf16x8 __attribute__((ext_vector_type(8)));
typedef float f32x4 __attribute__((ext_vector_type(4)));

#define AS1 __attribute__((address_space(1)))
#define AS3 __attribute__((address_space(3)))

__device__ __forceinline__ void async_copy16(const void* g, void* l) {
  // global -> LDS direct, 16B per lane. LDS dest = wave-uniform base + lane*16.
  __builtin_amdgcn_global_load_lds((const AS1 void*)g, (AS3 void*)l, 16, 0, 0);
}

// Problem constants
#define BB 8
#define CC 1024
#define QQ 128
#define EE 512
#define HH 1024
#define FOURE 2048

// ---------------------------------------------------------------------------
// K1: row dots: q_w[b,q] = question[b,q,:].w_question ; c_w[b,c] = context.w_context
// one wave per row. 9216 rows total.
// ---------------------------------------------------------------------------
__global__ __launch_bounds__(256) void rowdot_kernel(
    const float* __restrict__ qst, const float* __restrict__ ctx,
    const float* __restrict__ wq, const float* __restrict__ wc,
    float* __restrict__ qw, float* __restrict__ cw) {
  int gw = (blockIdx.x * 256 + threadIdx.x) >> 6;
  int ln = threadIdx.x & 63;
  const int NQ = BB * QQ;
  const float* src;
  const float* w;
  float* dst;
  if (gw < NQ) {
    src = qst + (size_t)gw * EE; w = wq; dst = qw + gw;
  } else {
    int i = gw - NQ;
    if (i >= BB * CC) return;
    src = ctx + (size_t)i * EE; w = wc; dst = cw + i;
  }
  float4 a0 = *(const float4*)&src[ln * 4];
  float4 w0 = *(const float4*)&w[ln * 4];
  float4 a1 = *(const float4*)&src[256 + ln * 4];
  float4 w1 = *(const float4*)&w[256 + ln * 4];
  float s = a0.x * w0.x + a0.y * w0.y + a0.z * w0.z + a0.w * w0.w +
            a1.x * w1.x + a1.y * w1.y + a1.z * w1.z + a1.w * w1.w;
#pragma unroll
  for (int off = 32; off; off >>= 1) s += __shfl_xor(s, off);
  if (ln == 0) *dst = s;
}

// ---------------------------------------------------------------------------
// Transpose + convert f32 -> bf16:  dst[C][R] = (bf16) src[R][C]. Batched.
// R, C multiples of 32. Block = 256 (32x8), 32x32 tile.
// ---------------------------------------------------------------------------
__global__ __launch_bounds__(256) void transpose_f32_bf16(
    const float* __restrict__ src, bf16* __restrict__ dst, int R, int C,
    long sSrc, long sDst) {
  int b = blockIdx.y;
  src += (size_t)b * sSrc;
  dst += (size_t)b * sDst;
  int ctiles = C >> 5;
  int by = blockIdx.x / ctiles, bx = blockIdx.x % ctiles;
  __shared__ float tile[32][33];
  int tx = threadIdx.x & 31, ty = threadIdx.x >> 5;
#pragma unroll
  for (int rr = 0; rr < 4; ++rr) {
    int r = by * 32 + ty + rr * 8;
    tile[ty + rr * 8][tx] = src[(size_t)r * C + bx * 32 + tx];
  }
  __syncthreads();
#pragma unroll
  for (int rr = 0; rr < 4; ++rr) {
    int dr = bx * 32 + ty + rr * 8;  // original column
    dst[(size_t)dr * R + by * 32 + tx] = (bf16)tile[tx][ty + rr * 8];
  }
}

// ---------------------------------------------------------------------------
// K3: sim GEMM (split-bf16 x3 for fp32-grade accuracy).
// sim[b, c, q] = sum_e ctx[b,c,e] * (qst[b,q,e]*wmul[e])  + qw[b,q] + cw[b,c]
// A = ctx (M=1024 rows per batch), Bt = qm (N=128 rows, K=E). 128x128 tile.
// ---------------------------------------------------------------------------
__global__ __launch_bounds__(256) void sim_gemm_kernel(
    const float* __restrict__ ctx, const float* __restrict__ qst,
    const float* __restrict__ wmul, const float* __restrict__ qw,
    const float* __restrict__ cw, float* __restrict__ sim) {
  int b = blockIdx.y;
  int m0 = blockIdx.x * 128;
  __shared__ bf16 Ah[128 * 32], Al[128 * 32], Bh[128 * 32], Bl[128 * 32];
  __shared__ float wm_s[EE];
  int t = threadIdx.x;
  for (int i = t; i < EE; i += 256) wm_s[i] = wmul[i];
  int wv = t >> 6, ln = t & 63;
  int wm = wv >> 1, wn = wv & 1;
  f32x4 acc[4][4] = {};
  const float* Ag = ctx + (size_t)b * CC * EE + (size_t)m0 * EE;
  const float* Bg = qst + (size_t)b * QQ * EE;
  int row = t >> 1, col0 = (t & 1) * 16;
  __syncthreads();
  for (int k0 = 0; k0 < EE; k0 += 32) {
    // stage A (ctx) hi/lo
    {
      const float4* s4 = (const float4*)(Ag + (size_t)row * EE + k0 + col0);
      float vals[16];
#pragma unroll
      for (int p = 0; p < 4; ++p) {
        float4 v = s4[p];
        vals[p * 4 + 0] = v.x; vals[p * 4 + 1] = v.y;
        vals[p * 4 + 2] = v.z; vals[p * 4 + 3] = v.w;
      }
      bf16x8 h0, h1, l0, l1;
#pragma unroll
      for (int i = 0; i < 8; ++i) {
        bf16 hh = (bf16)vals[i];
        h0[i] = hh; l0[i] = (bf16)(vals[i] - (float)hh);
        hh = (bf16)vals[8 + i];
        h1[i] = hh; l1[i] = (bf16)(vals[8 + i] - (float)hh);
      }
      *(bf16x8*)&Ah[row * 32 + col0] = h0;
      *(bf16x8*)&Ah[row * 32 + col0 + 8] = h1;
      *(bf16x8*)&Al[row * 32 + col0] = l0;
      *(bf16x8*)&Al[row * 32 + col0 + 8] = l1;
    }
    // stage B (question * wmul) hi/lo   (row here = q in 0..127)
    {
      const float4* s4 = (const float4*)(Bg + (size_t)row * EE + k0 + col0);
      float vals[16];
#pragma unroll
      for (int p = 0; p < 4; ++p) {
        float4 v = s4[p];
        vals[p * 4 + 0] = v.x; vals[p * 4 + 1] = v.y;
        vals[p * 4 + 2] = v.z; vals[p * 4 + 3] = v.w;
      }
#pragma unroll
      for (int i = 0; i < 16; ++i) vals[i] *= wm_s[k0 + col0 + i];
      bf16x8 h0, h1, l0, l1;
#pragma unroll
      for (int i = 0; i < 8; ++i) {
        bf16 hh = (bf16)vals[i];
        h0[i] = hh; l0[i] = (bf16)(vals[i] - (float)hh);
        hh = (bf16)vals[8 + i];
        h1[i] = hh; l1[i] = (bf16)(vals[8 + i] - (float)hh);
      }
      *(bf16x8*)&Bh[row * 32 + col0] = h0;
      *(bf16x8*)&Bh[row * 32 + col0 + 8] = h1;
      *(bf16x8*)&Bl[row * 32 + col0] = l0;
      *(bf16x8*)&Bl[row * 32 + col0 + 8] = l1;
    }
    __syncthreads();
    int ke = (ln >> 4) * 8;
    bf16x8 ah[4], al[4], bh[4], bl[4];
#pragma unroll
    for (int i = 0; i < 4; ++i) {
      int rr = wm * 64 + i * 16 + (ln & 15);
      ah[i] = *(const bf16x8*)&Ah[rr * 32 + ke];
      al[i] = *(const bf16x8*)&Al[rr * 32 + ke];
    }
#pragma unroll
    for (int j = 0; j < 4; ++j) {
      int nn = wn * 64 + j * 16 + (ln & 15);
      bh[j] = *(const bf16x8*)&Bh[nn * 32 + ke];
      bl[j] = *(const bf16x8*)&Bl[nn * 32 + ke];
    }
#pragma unroll
    for (int i = 0; i < 4; ++i)
#pragma unroll
      for (int j = 0; j < 4; ++j) {
        acc[i][j] = __builtin_amdgcn_mfma_f32_16x16x32_bf16(ah[i], bh[j], acc[i][j], 0, 0, 0);
        acc[i][j] = __builtin_amdgcn_mfma_f32_16x16x32_bf16(ah[i], bl[j], acc[i][j], 0, 0, 0);
        acc[i][j] = __builtin_amdgcn_mfma_f32_16x16x32_bf16(al[i], bh[j], acc[i][j], 0, 0, 0);
      }
    __syncthreads();
  }
  // epilogue: + qw[q] + cw[c], write fp32 sim
  const float* qwb = qw + b * QQ;
  const float* cwb = cw + b * CC + m0;
  float* simb = sim + ((size_t)b * CC + m0) * QQ;
#pragma unroll
  for (int j = 0; j < 4; ++j) {
    int col = wn * 64 + j * 16 + (ln & 15);
    float qv = qwb[col];
#pragma unroll
    for (int i = 0; i < 4; ++i) {
      int rbase = wm * 64 + i * 16 + ((ln >> 4) << 2);
#pragma unroll
      for (int r = 0; r < 4; ++r) {
        int rowl = rbase + r;
        simb[(size_t)rowl * QQ + col] = acc[i][j][r] + qv + cwb[rowl];
      }
    }
  }
}

// ---------------------------------------------------------------------------
// K4: softmax over q (128 values) per (b,c) row. One wave per row.
// Writes P (bf16) and smax (row max, fp32).
// ---------------------------------------------------------------------------
__global__ __launch_bounds__(256) void softmax_q_kernel(
    const float* __restrict__ sim, bf16* __restrict__ P, float* __restrict__ smax) {
  int row = blockIdx.x * 4 + (threadIdx.x >> 6);
  int ln = threadIdx.x & 63;
  const float* s = sim + (size_t)row * QQ;
  float v0 = s[ln], v1 = s[64 + ln];
  float mx = fmaxf(v0, v1);
#pragma unroll
  for (int off = 32; off; off >>= 1) mx = fmaxf(mx, __shfl_xor(mx, off));
  float e0 = __expf(v0 - mx), e1 = __expf(v1 - mx);
  float sm = e0 + e1;
#pragma unroll
  for (int off = 32; off; off >>= 1) sm += __shfl_xor(sm, off);
  float inv = 1.0f / sm;
  P[(size_t)row * QQ + ln] = (bf16)(e0 * inv);
  P[(size_t)row * QQ + 64 + ln] = (bf16)(e1 * inv);
  if (ln == 0) smax[row] = mx;
}

// ---------------------------------------------------------------------------
// K5: softmax over c (1024) per b. One block per b.
// ---------------------------------------------------------------------------
__global__ __launch_bounds__(256) void softmax_c_kernel(
    const float* __restrict__ smax, float* __restrict__ cwt) {
  int b = blockIdx.x, t = threadIdx.x;
  __shared__ float red[256];
  float v[4];
  float mx = -3.4e38f;
#pragma unroll
  for (int i = 0; i < 4; ++i) {
    v[i] = smax[b * CC + i * 256 + t];
    mx = fmaxf(mx, v[i]);
  }
  red[t] = mx;
  __syncthreads();
  for (int s = 128; s > 0; s >>= 1) {
    if (t < s) red[t] = fmaxf(red[t], red[t + s]);
    __syncthreads();
  }
  mx = red[0];
  __syncthreads();
  float e[4], sm = 0.f;
#pragma unroll
  for (int i = 0; i < 4; ++i) { e[i] = __expf(v[i] - mx); sm += e[i]; }
  red[t] = sm;
  __syncthreads();
  for (int s = 128; s > 0; s >>= 1) {
    if (t < s) red[t] += red[t + s];
    __syncthreads();
  }
  float inv = 1.0f / red[0];
#pragma unroll
  for (int i = 0; i < 4; ++i) cwt[b * CC + i * 256 + t] = e[i] * inv;
}

// ---------------------------------------------------------------------------
// K6: q2c[b,e] = sum_c cwt[b,c] * ctx[b,c,e].  Grid = (b * 8 egroups of 64).
// ---------------------------------------------------------------------------
__global__ __launch_bounds__(256) void q2c_kernel(
    const float* __restrict__ ctx, const float* __restrict__ cwt,
    float* __restrict__ q2c) {
  int b = blockIdx.x >> 3, g = blockIdx.x & 7;
  int t = threadIdx.x;
  int e = g * 64 + (t & 63), cq = t >> 6;
  __shared__ float red[4][64];
  float acc = 0.f;
  const float* cb = ctx + (size_t)b * CC * EE;
  const float* wb = cwt + b * CC;
  for (int c = cq * 256; c < cq * 256 + 256; ++c)
    acc += wb[c] * cb[(size_t)c * EE + e];
  red[cq][t & 63] = acc;
  __syncthreads();
  if (cq == 0)
    q2c[b * EE + e] = red[0][t] + red[1][t] + red[2][t] + red[3][t];
}

// ---------------------------------------------------------------------------
// K7: build attended (bf16): [ctx | c2q | ctx*c2q | ctx*q2c[b]]
// ---------------------------------------------------------------------------
__global__ __launch_bounds__(256) void attbuild_kernel(
    const float* __restrict__ ctx, const bf16* __restrict__ c2q,
    const float* __restrict__ q2c, bf16* __restrict__ att) {
  int idx = blockIdx.x * 256 + threadIdx.x;  // over (row, e/4)
  int row = idx >> 7;
  int e = (idx & 127) * 4;
  int b = row >> 10;
  float4 cv = *(const float4*)&ctx[(size_t)row * EE + e];
  bf16x4 qv = *(const bf16x4*)&c2q[(size_t)row * EE + e];
  float4 gv = *(const float4*)&q2c[b * EE + e];
  bf16* dst = att + (size_t)row * FOURE;
  bf16x4 o0, o2, o3;
  o0[0] = (bf16)cv.x; o0[1] = (bf16)cv.y; o0[2] = (bf16)cv.z; o0[3] = (bf16)cv.w;
  o2[0] = (bf16)(cv.x * (float)qv[0]); o2[1] = (bf16)(cv.y * (float)qv[1]);
  o2[2] = (bf16)(cv.z * (float)qv[2]); o2[3] = (bf16)(cv.w * (float)qv[3]);
  o3[0] = (bf16)(cv.x * gv.x); o3[1] = (bf16)(cv.y * gv.y);
  o3[2] = (bf16)(cv.z * gv.z); o3[3] = (bf16)(cv.w * gv.w);
  *(bf16x4*)&dst[e] = o0;
  *(bf16x4*)&dst[512 + e] = qv;
  *(bf16x4*)&dst[1024 + e] = o2;
  *(bf16x4*)&dst[1536 + e] = o3;
}

// ---------------------------------------------------------------------------
// Generic bf16 GEMM (m97 structure): C = A(MxK) @ Bt(NxK)^T, 128x128 tile,
// BK=32, global_load_lds width-16 staging, 16x16x32 bf16 MFMA.
// Epilogue: optional bias[col], mask[row], relu; out bf16 or f32. Batched.
// ---------------------------------------------------------------------------
template <int OUT_BF16, int RELU, int HAS_BIAS, int HAS_MASK>
__global__ __launch_bounds__(256) void gemm_bt_kernel(
    const bf16* __restrict__ A, const bf16* __restrict__ Bt,
    const float* __restrict__ bias, const float* __restrict__ mask,
    void* __restrict__ Cout, int M, int N, int K, long sA, long sB, long sC) {
  int b = blockIdx.y;
  A += (size_t)b * sA;
  Bt += (size_t)b * sB;
  int ntiles = N >> 7;
  int mt = blockIdx.x / ntiles, ntb = blockIdx.x % ntiles;
  int m0 = mt << 7, n0 = ntb << 7;
  __shared__ bf16 As[128 * 32];
  __shared__ bf16 Bs[128 * 32];
  int t = threadIdx.x, wv = t >> 6, ln = t & 63;
  int wm = wv >> 1, wn = wv & 1;
  f32x4 acc[4][4] = {};
  for (int k0 = 0; k0 < K; k0 += 32) {
#pragma unroll
    for (int r = 0; r < 2; ++r) {
      int fb = r * 4096 + wv * 1024 + ln * 16;  // byte offset within 8KB tile
      int row = fb >> 6;
      int cole = (fb & 63) >> 1;  // element offset within 32-elem row
      const bf16* ga = A + (size_t)(m0 + row) * K + k0 + cole;
      const bf16* gb = Bt + (size_t)(n0 + row) * K + k0 + cole;
      async_copy16(ga, As + r * 2048 + wv * 512);
      async_copy16(gb, Bs + r * 2048 + wv * 512);
    }
    __syncthreads();
    int ke = (ln >> 4) * 8;
    bf16x8 af[4], bfr[4];
#pragma unroll
    for (int i = 0; i < 4; ++i)
      af[i] = *(const bf16x8*)&As[(wm * 64 + i * 16 + (ln & 15)) * 32 + ke];
#pragma unroll
    for (int j = 0; j < 4; ++j)
      bfr[j] = *(const bf16x8*)&Bs[(wn * 64 + j * 16 + (ln & 15)) * 32 + ke];
#pragma unroll
    for (int i = 0; i < 4; ++i)
#pragma unroll
      for (int j = 0; j < 4; ++j)
        acc[i][j] = __builtin_amdgcn_mfma_f32_16x16x32_bf16(af[i], bfr[j], acc[i][j], 0, 0, 0);
    __syncthreads();
  }
  size_t outbase = (size_t)b * sC;
#pragma unroll
  for (int j = 0; j < 4; ++j) {
    int col = n0 + wn * 64 + j * 16 + (ln & 15);
    float bv = HAS_BIAS ? bias[col] : 0.f;
#pragma unroll
    for (int i = 0; i < 4; ++i) {
      int rbase = m0 + wm * 64 + i * 16 + ((ln >> 4) << 2);
#pragma unroll
      for (int r = 0; r < 4; ++r) {
        int row = rbase + r;
        float v = acc[i][j][r] + bv;
        if (HAS_MASK) v *= mask[row];
        if (RELU) v = fmaxf(v, 0.f);
        if (OUT_BF16)
          ((bf16*)Cout)[outbase + (size_t)row * N + col] = (bf16)v;
        else
          ((float*)Cout)[outbase + (size_t)row * N + col] = v;
      }
    }
  }
}

// ---------------------------------------------------------------------------
// launcher
// ---------------------------------------------------------------------------
extern "C" void kernel_launch(void* const* d_in, const int* in_sizes, int n_in,
                              void* d_out, int out_size, void* d_ws, size_t ws_size,
                              hipStream_t stream) {
  const float* ctx = (const float*)d_in[0];
  const float* qst = (const float*)d_in[1];
  const float* mask = (const float*)d_in[2];
  const float* wq = (const float*)d_in[3];
  const float* wc = (const float*)d_in[4];
  const float* wmul = (const float*)d_in[5];
  const float* W1 = (const float*)d_in[6];
  const float* b1 = (const float*)d_in[7];
  const float* W2 = (const float*)d_in[8];
  const float* b2 = (const float*)d_in[9];
  float* out = (float*)d_out;
  char* ws = (char*)d_ws;

  // workspace layout (bytes)
  bf16* att  = (bf16*)(ws);                    // 8192*2048*2 = 33554432
  bf16* hbuf = (bf16*)(ws + 33554432);         // 8192*1024*2 = 16777216
  bf16* W1T  = (bf16*)(ws + 50331648);         // 1024*2048*2 = 4194304
  bf16* W2T  = (bf16*)(ws + 54525952);         // 2048*1024*2 = 4194304
  bf16* qT   = (bf16*)(ws + 58720256);         // 8*512*128*2 = 1048576
  float* sim = (float*)(ws + 59768832);        // 8192*128*4  = 4194304
  bf16* P    = (bf16*)(ws + 63963136);         // 8192*128*2  = 2097152
  bf16* c2q  = (bf16*)(ws + 66060288);         // 8192*512*2  = 8388608
  float* qw   = (float*)(ws + 74448896);       // 4096
  float* cw   = (float*)(ws + 74452992);       // 32768
  float* smax = (float*)(ws + 74485760);       // 32768
  float* cwt  = (float*)(ws + 74518528);       // 32768
  float* q2c  = (float*)(ws + 74551296);       // 16384   (end ~74.6MB)

  // 1) row dots
  rowdot_kernel<<<2304, 256, 0, stream>>>(qst, ctx, wq, wc, qw, cw);
  // 2) weight / question transposes (f32 -> bf16, Bt layout)
  transpose_f32_bf16<<<dim3(2048, 1), 256, 0, stream>>>(W1, W1T, 2048, 1024, 0, 0);
  transpose_f32_bf16<<<dim3(2048, 1), 256, 0, stream>>>(W2, W2T, 1024, 2048, 0, 0);
  transpose_f32_bf16<<<dim3(64, BB), 256, 0, stream>>>(qst, qT, 128, 512,
                                                       (long)QQ * EE, (long)EE * QQ);
  // 3) sim (split-bf16 MFMA, fp32 out)
  sim_gemm_kernel<<<dim3(8, BB), 256, 0, stream>>>(ctx, qst, wmul, qw, cw, sim);
  // 4) softmax over q -> P, smax
  softmax_q_kernel<<<2048, 256, 0, stream>>>(sim, P, smax);
  // 5) softmax over c
  softmax_c_kernel<<<BB, 256, 0, stream>>>(smax, cwt);
  // 6) q2c
  q2c_kernel<<<64, 256, 0, stream>>>(ctx, cwt, q2c);
  // 7) c2q = P @ question  (batched, bf16 out)
  gemm_bt_kernel<1, 0, 0, 0><<<dim3(32, BB), 256, 0, stream>>>(
      P, qT, nullptr, nullptr, c2q, 1024, 512, 128,
      (long)CC * QQ, (long)EE * QQ, (long)CC * EE);
  // 8) attended build
  attbuild_kernel<<<4096, 256, 0, stream>>>(ctx, c2q, q2c, att);
  // 9) h = (att @ W1 + b1) * mask   (bf16 out)
  gemm_bt_kernel<1, 0, 1, 1><<<dim3(512, 1), 256, 0, stream>>>(
      att, W1T, b1, mask, hbuf, 8192, 1024, 2048, 0, 0, 0);
  // 10) out = relu((h @ W2 + b2) * mask)  (f32 out)
  gemm_bt_kernel<0, 1, 1, 1><<<dim3(1024, 1), 256, 0, stream>>>(
      hbuf, W2T, b2, mask, out, 8192, 2048, 1024, 0, 0, 0);
}